// Round 7
// baseline (162.072 us; speedup 1.0000x reference)
//
#include <hip/hip_runtime.h>
#include <math.h>

// Problem constants (from reference setup_inputs)
#define B_    8
#define H_    32
#define D_    128
#define SMAX_ 4096
#define HD_   (H_ * D_)
#define SCALE 0.5f
#define PSTRIDE (D_ + 2)     // partial record per (split, head): m, l, acc[128]
#define NSPLIT 16
#define CHUNK  256           // positions per split (NSPLIT*CHUNK = SMAX)

// native clang vector type (HIP_vector_type is rejected by the nt builtin)
typedef float vfloat4 __attribute__((ext_vector_type(4)));

__device__ __forceinline__ vfloat4 ntload4(const float* p) {
    return __builtin_nontemporal_load((const vfloat4*)p);
}

// ---------------------------------------------------------------------------
// Kernel 1: flash-decode partials (R1 structure, densified streams + nt loads).
// grid = B*H*NSPLIT = 4096 blocks, 256 threads. Block (bh, split) handles
// positions [split*256, split*256+256) for one (b,h). Each 16-lane group g
// owns a CONTIGUOUS run of 16 positions [cs+g*16, cs+g*16+16): its loads
// stride 16 KB (dense), vs R1's every-16th (256 KB stride). lane (tid&15)
// owns d-slice (tid&15)*8 -> group reads 512 B K + 512 B V per position.
// Units are uniform 256 KB -> good dynamic balance (R1's accidental win).
// Online softmax per group; shfl merge groups in wave; LDS merge waves.
// ---------------------------------------------------------------------------
__global__ __launch_bounds__(256, 4)
void attn_partial(const float* __restrict__ q,
                  const float* __restrict__ knew,
                  const float* __restrict__ vnew,
                  const float* __restrict__ kcache,
                  const float* __restrict__ vcache,
                  const int* __restrict__ seqlen,
                  float* __restrict__ ws,
                  float* __restrict__ out)
{
    const int blk   = blockIdx.x;
    const int split = blk & (NSPLIT - 1);
    const int bh    = blk / NSPLIT;
    const int h     = bh & (H_ - 1);
    const int b     = bh / H_;

    const int sl    = seqlen[b];
    const int total = sl + 1;                  // positions 0..sl (sl = new token)
    const int cs    = split * CHUNK;
    const int ce    = min(cs + CHUNK, total);

    const int tid    = threadIdx.x;
    const int lane16 = tid & 15;
    const int gid    = tid >> 4;               // 16 groups

    const int qbase = (b * H_ + h) * D_ + lane16 * 8;
    float qf[8];
    {
        float4 q0 = *(const float4*)(q + qbase);
        float4 q1 = *(const float4*)(q + qbase + 4);
        qf[0]=q0.x; qf[1]=q0.y; qf[2]=q0.z; qf[3]=q0.w;
        qf[4]=q1.x; qf[5]=q1.y; qf[6]=q1.z; qf[7]=q1.w;
    }

    float m = -1e30f, l = 0.f;                 // -1e30 sentinel, NOT -inf
    float acc[8];
    #pragma unroll
    for (int j = 0; j < 8; ++j) acc[j] = 0.f;

    const size_t cbase = (size_t)b * SMAX_ * HD_ + (size_t)h * D_ + (size_t)(lane16 * 8);

#define STEP1(KP, VP) do {                                                    \
    vfloat4 k0 = ntload4(KP);                                                 \
    vfloat4 k1 = ntload4((KP)+4);                                             \
    vfloat4 v0 = ntload4(VP);                                                 \
    vfloat4 v1 = ntload4((VP)+4);                                             \
    float s = qf[0]*k0.x+qf[1]*k0.y+qf[2]*k0.z+qf[3]*k0.w                     \
            + qf[4]*k1.x+qf[5]*k1.y+qf[6]*k1.z+qf[7]*k1.w;                    \
    s += __shfl_xor(s, 1); s += __shfl_xor(s, 2);                             \
    s += __shfl_xor(s, 4); s += __shfl_xor(s, 8);                             \
    s *= SCALE;                                                               \
    float mn = fmaxf(m, s);                                                   \
    float sc = __expf(m - mn);                                                \
    float pr = __expf(s - mn);                                                \
    m = mn; l = l * sc + pr;                                                  \
    acc[0]=fmaf(pr,v0.x,acc[0]*sc); acc[1]=fmaf(pr,v0.y,acc[1]*sc);           \
    acc[2]=fmaf(pr,v0.z,acc[2]*sc); acc[3]=fmaf(pr,v0.w,acc[3]*sc);           \
    acc[4]=fmaf(pr,v1.x,acc[4]*sc); acc[5]=fmaf(pr,v1.y,acc[5]*sc);           \
    acc[6]=fmaf(pr,v1.z,acc[6]*sc); acc[7]=fmaf(pr,v1.w,acc[7]*sc);           \
} while (0)

    // this group's contiguous run of positions
    const int gs   = cs + gid * (CHUNK / 16);
    const int ge   = min(gs + (CHUNK / 16), ce);
    const int pend = min(ge, sl);              // cache-resident part

    const float* kp = kcache + cbase + (size_t)gs * HD_;
    const float* vp = vcache + cbase + (size_t)gs * HD_;

    int p = gs;
    // unroll-2: consecutive positions, 8 float4 loads in flight per thread
    for (; p + 2 <= pend; p += 2) {
        vfloat4 a0 = ntload4(kp);
        vfloat4 a1 = ntload4(kp + 4);
        vfloat4 b0 = ntload4(kp + HD_);
        vfloat4 b1 = ntload4(kp + HD_ + 4);
        vfloat4 u0 = ntload4(vp);
        vfloat4 u1 = ntload4(vp + 4);
        vfloat4 w0 = ntload4(vp + HD_);
        vfloat4 w1 = ntload4(vp + HD_ + 4);

        float s0 = qf[0]*a0.x+qf[1]*a0.y+qf[2]*a0.z+qf[3]*a0.w
                 + qf[4]*a1.x+qf[5]*a1.y+qf[6]*a1.z+qf[7]*a1.w;
        float s1 = qf[0]*b0.x+qf[1]*b0.y+qf[2]*b0.z+qf[3]*b0.w
                 + qf[4]*b1.x+qf[5]*b1.y+qf[6]*b1.z+qf[7]*b1.w;
        s0 += __shfl_xor(s0, 1); s0 += __shfl_xor(s0, 2);
        s0 += __shfl_xor(s0, 4); s0 += __shfl_xor(s0, 8);
        s1 += __shfl_xor(s1, 1); s1 += __shfl_xor(s1, 2);
        s1 += __shfl_xor(s1, 4); s1 += __shfl_xor(s1, 8);
        s0 *= SCALE; s1 *= SCALE;

        float mn  = fmaxf(m, fmaxf(s0, s1));
        float sc  = __expf(m - mn);
        float pr0 = __expf(s0 - mn);
        float pr1 = __expf(s1 - mn);
        m = mn;
        l = l * sc + pr0 + pr1;
        acc[0] = fmaf(pr1,w0.x, fmaf(pr0,u0.x, acc[0]*sc));
        acc[1] = fmaf(pr1,w0.y, fmaf(pr0,u0.y, acc[1]*sc));
        acc[2] = fmaf(pr1,w0.z, fmaf(pr0,u0.z, acc[2]*sc));
        acc[3] = fmaf(pr1,w0.w, fmaf(pr0,u0.w, acc[3]*sc));
        acc[4] = fmaf(pr1,w1.x, fmaf(pr0,u1.x, acc[4]*sc));
        acc[5] = fmaf(pr1,w1.y, fmaf(pr0,u1.y, acc[5]*sc));
        acc[6] = fmaf(pr1,w1.z, fmaf(pr0,u1.z, acc[6]*sc));
        acc[7] = fmaf(pr1,w1.w, fmaf(pr0,u1.w, acc[7]*sc));
        kp += 2 * HD_;
        vp += 2 * HD_;
    }
    if (p < pend) {
        STEP1(kp, vp);
    }
    // appended token (position sl) from knew/vnew, if in this group's run
    if (sl >= gs && sl < ge) {
        const float* kn = knew + qbase;
        const float* vn = vnew + qbase;
        STEP1(kn, vn);
    }
#undef STEP1

    // merge the 4 groups within each wave (same lane16 = same d-slice)
    #pragma unroll
    for (int off = 16; off <= 32; off <<= 1) {
        float m2 = __shfl_xor(m, off);
        float l2 = __shfl_xor(l, off);
        float a2[8];
        #pragma unroll
        for (int j = 0; j < 8; ++j) a2[j] = __shfl_xor(acc[j], off);
        float mn = fmaxf(m, m2);
        float s1 = __expf(m - mn);
        float s2 = __expf(m2 - mn);
        l = l * s1 + l2 * s2;
        #pragma unroll
        for (int j = 0; j < 8; ++j) acc[j] = acc[j]*s1 + a2[j]*s2;
        m = mn;
    }

    // merge the 4 waves via LDS
    __shared__ float sm_m[4];
    __shared__ float sm_l[4];
    __shared__ float sm_acc[4][D_];
    const int w    = tid >> 6;
    const int lane = tid & 63;
    if (lane < 16) {
        if (lane == 0) { sm_m[w] = m; sm_l[w] = l; }
        #pragma unroll
        for (int j = 0; j < 8; ++j) sm_acc[w][lane16*8 + j] = acc[j];
    }
    __syncthreads();

    if (tid < D_) {
        float m0 = sm_m[0], m1 = sm_m[1], m2 = sm_m[2], m3 = sm_m[3];
        float mt = fmaxf(fmaxf(m0, m1), fmaxf(m2, m3));
        float e0 = __expf(m0 - mt), e1 = __expf(m1 - mt);
        float e2 = __expf(m2 - mt), e3 = __expf(m3 - mt);
        float lt = sm_l[0]*e0 + sm_l[1]*e1 + sm_l[2]*e2 + sm_l[3]*e3;
        float a  = sm_acc[0][tid]*e0 + sm_acc[1][tid]*e1
                 + sm_acc[2][tid]*e2 + sm_acc[3][tid]*e3;
        float* wsp = ws + (size_t)blk * PSTRIDE;
        if (tid == 0) { wsp[0] = mt; wsp[1] = lt; }
        wsp[2 + tid] = a;
    }
}

// ---------------------------------------------------------------------------
// Kernel 2: combine partials. grid = B*H blocks, 128 threads. (R1 proven)
// ---------------------------------------------------------------------------
__global__ __launch_bounds__(128)
void attn_combine(const float* __restrict__ ws, float* __restrict__ out)
{
    const int bh = blockIdx.x;
    const int d  = threadIdx.x;
    const float* base = ws + (size_t)bh * NSPLIT * PSTRIDE;

    float mt = -1e30f;
    #pragma unroll
    for (int s = 0; s < NSPLIT; ++s) mt = fmaxf(mt, base[(size_t)s * PSTRIDE]);
    float lt = 0.f, a = 0.f;
    #pragma unroll
    for (int s = 0; s < NSPLIT; ++s) {
        const float* p = base + (size_t)s * PSTRIDE;
        float ls = p[1];
        float e  = (ls > 0.f) ? __expf(p[0] - mt) : 0.f;   // empty split -> 0
        lt += ls * e;
        a  += p[2 + d] * e;
    }
    out[bh * D_ + d] = a / lt;
}

extern "C" void kernel_launch(void* const* d_in, const int* in_sizes, int n_in,
                              void* d_out, int out_size, void* d_ws, size_t ws_size,
                              hipStream_t stream) {
    const float* q  = (const float*)d_in[0];
    const float* k  = (const float*)d_in[1];
    const float* v  = (const float*)d_in[2];
    const float* kc = (const float*)d_in[3];
    const float* vc = (const float*)d_in[4];
    const int*   sl = (const int*)d_in[5];
    float* out = (float*)d_out;
    float* ws  = (float*)d_ws;

    // ws need: 8*32*16*130*4 = ~2.1 MB (well under ws_size)
    attn_partial<<<B_ * H_ * NSPLIT, 256, 0, stream>>>(q, k, v, kc, vc, sl, ws, out);
    attn_combine<<<B_ * H_, 128, 0, stream>>>(ws, out);
}